// Round 1
// 732.230 us; speedup vs baseline: 1.0119x; 1.0119x over previous
//
#include <hip/hip_runtime.h>
#include <hip/hip_bf16.h>

// MultiHeadAttention  B=4, L=1024, H=16, U=64, D_IN=1024, D_MODEL=1024
// Round 2: register-resident softmax in attn_fused.
//   - logits kept in 16x f4v registers per wave (no 64KB fp32 LDS tile)
//   - row max/sum: in-lane reduce + 16-lane shfl_xor + 512B cross-wave LDS
//   - P stored once as bf16 (32KB LDS, XOR-swizzled) -> 4 blocks/CU (was 2)
//   - attn written nontemporal from fp32 regs (keep L2 for Q/K/V)
//   - XCD-bijective block swizzle: same-bh blocks share one XCD's L2

typedef __attribute__((ext_vector_type(8))) short s8v;   // 8 bf16 = 4 VGPR
typedef __attribute__((ext_vector_type(4))) float f4v;   // MFMA C/D

#define MFMA16(a, b, c) __builtin_amdgcn_mfma_f32_16x16x32_bf16(a, b, c, 0, 0, 0)

__device__ __forceinline__ ushort f2bf(float x) {
    unsigned u = __float_as_uint(x);
    return (ushort)((u + 0x7FFF + ((u >> 16) & 1)) >> 16);  // RNE
}
__device__ __forceinline__ void split2(float x, ushort& h, ushort& l) {
    h = f2bf(x);
    float hf = __uint_as_float(((unsigned)h) << 16);
    l = f2bf(x - hf);
}

// ---------------------------------------------------------------- pack_wt ----
// W[k][n] fp32 -> Wt_hi[n][k], Wt_lo[n][k] bf16 (transpose + split), 1024x1024.
__global__ __launch_bounds__(256) void pack_wt(const float* __restrict__ W,
                                               ushort* __restrict__ Wt_hi,
                                               ushort* __restrict__ Wt_lo) {
    __shared__ float tile[32][36];
    const int t = threadIdx.x;
    const int n0 = blockIdx.x * 32, k0 = blockIdx.y * 32;
    {
        const int kr = t >> 3, c4 = (t & 7) * 4;
        float4 v = *(const float4*)&W[(size_t)(k0 + kr) * 1024 + n0 + c4];
        *(float4*)&tile[kr][c4] = v;
    }
    __syncthreads();
    {
        const int n = t >> 3, k4 = (t & 7) * 4;
        ushort4 h, l;
        split2(tile[k4 + 0][n], h.x, l.x);
        split2(tile[k4 + 1][n], h.y, l.y);
        split2(tile[k4 + 2][n], h.z, l.z);
        split2(tile[k4 + 3][n], h.w, l.w);
        *(ushort4*)&Wt_hi[(size_t)(n0 + n) * 1024 + k0 + k4] = h;
        *(ushort4*)&Wt_lo[(size_t)(n0 + n) * 1024 + k0 + k4] = l;
    }
}

// -------------------------------------------------------------- gemm_proj ----
// X(4096x1024 fp32) @ W (via Wt bf16 [n][k]) + bias -> head-split bf16 out.
// 128x128 tile, BK=32, 256 thr (4 waves, each 64x64 = 4x4 tiles of 16x16x32).
#define PROJ_LDSTRIDE 40
template <bool SPLIT>
__global__ __launch_bounds__(256, 2) void gemm_proj_mfma(
    const float* __restrict__ X, const ushort* __restrict__ Wt_hi,
    const ushort* __restrict__ Wt_lo, const float* __restrict__ bias,
    ushort* __restrict__ Yhi, ushort* __restrict__ Ylo) {
    __shared__ ushort As_hi[128 * PROJ_LDSTRIDE];
    __shared__ ushort As_lo[128 * PROJ_LDSTRIDE];
    __shared__ ushort Bs_hi[128 * PROJ_LDSTRIDE];
    __shared__ ushort Bs_lo[128 * PROJ_LDSTRIDE];

    const int t = threadIdx.x;
    const int lane = t & 63, w = t >> 6;
    const int wm = (w & 1) * 64, wn = (w >> 1) * 64;
    const int fr = lane & 15, q8 = (lane >> 4) * 8;
    const int row0 = blockIdx.y * 128, col0 = blockIdx.x * 128;

    const int srow = t >> 1, skb = (t & 1) * 16;

    f4v acc[4][4] = {};

    for (int k0 = 0; k0 < 1024; k0 += 32) {
        {
            const float* xp = &X[(size_t)(row0 + srow) * 1024 + k0 + skb];
#pragma unroll
            for (int j = 0; j < 4; ++j) {
                float4 x4 = *(const float4*)&xp[4 * j];
                ushort4 h, l;
                split2(x4.x, h.x, l.x);
                split2(x4.y, h.y, l.y);
                split2(x4.z, h.z, l.z);
                split2(x4.w, h.w, l.w);
                *(ushort4*)&As_hi[srow * PROJ_LDSTRIDE + skb + 4 * j] = h;
                if (SPLIT) *(ushort4*)&As_lo[srow * PROJ_LDSTRIDE + skb + 4 * j] = l;
            }
        }
        {
            const ushort* bp = &Wt_hi[(size_t)(col0 + srow) * 1024 + k0 + skb];
            *(uint4*)&Bs_hi[srow * PROJ_LDSTRIDE + skb] = *(const uint4*)bp;
            *(uint4*)&Bs_hi[srow * PROJ_LDSTRIDE + skb + 8] = *(const uint4*)(bp + 8);
            if (SPLIT) {
                const ushort* bl = &Wt_lo[(size_t)(col0 + srow) * 1024 + k0 + skb];
                *(uint4*)&Bs_lo[srow * PROJ_LDSTRIDE + skb] = *(const uint4*)bl;
                *(uint4*)&Bs_lo[srow * PROJ_LDSTRIDE + skb + 8] = *(const uint4*)(bl + 8);
            }
        }
        __syncthreads();

        s8v a_hi[4], a_lo[4], b_hi[4], b_lo[4];
#pragma unroll
        for (int mi = 0; mi < 4; ++mi) {
            a_hi[mi] = *(const s8v*)&As_hi[(wm + mi * 16 + fr) * PROJ_LDSTRIDE + q8];
            if (SPLIT) a_lo[mi] = *(const s8v*)&As_lo[(wm + mi * 16 + fr) * PROJ_LDSTRIDE + q8];
        }
#pragma unroll
        for (int ni = 0; ni < 4; ++ni) {
            b_hi[ni] = *(const s8v*)&Bs_hi[(wn + ni * 16 + fr) * PROJ_LDSTRIDE + q8];
            if (SPLIT) b_lo[ni] = *(const s8v*)&Bs_lo[(wn + ni * 16 + fr) * PROJ_LDSTRIDE + q8];
        }
#pragma unroll
        for (int mi = 0; mi < 4; ++mi)
#pragma unroll
            for (int ni = 0; ni < 4; ++ni) {
                acc[mi][ni] = MFMA16(a_hi[mi], b_hi[ni], acc[mi][ni]);
                if (SPLIT) {
                    acc[mi][ni] = MFMA16(a_hi[mi], b_lo[ni], acc[mi][ni]);
                    acc[mi][ni] = MFMA16(a_lo[mi], b_hi[ni], acc[mi][ni]);
                }
            }
        __syncthreads();
    }

#pragma unroll
    for (int mi = 0; mi < 4; ++mi)
#pragma unroll
        for (int ni = 0; ni < 4; ++ni)
#pragma unroll
            for (int r = 0; r < 4; ++r) {
                const int lr = wm + mi * 16 + (lane >> 4) * 4 + r;
                const int lc = wn + ni * 16 + fr;
                const int grow = row0 + lr;
                const int b = grow >> 10, ll = grow & 1023;
                const int gcol = col0 + lc;
                const int h = gcol >> 6, u = gcol & 63;
                const float val = acc[mi][ni][r] + bias[gcol];
                const size_t o = ((size_t)((b * 16 + h) * 1024 + ll)) * 64 + u;
                if (SPLIT) {
                    ushort hh, lll;
                    split2(val, hh, lll);
                    Yhi[o] = hh;
                    Ylo[o] = lll;
                } else {
                    Yhi[o] = f2bf(val);
                }
            }
}

// --------------------------------------------------------------- trans_vh ----
__global__ __launch_bounds__(256) void trans_vh(const ushort* __restrict__ vh,
                                                ushort* __restrict__ vhT) {
    __shared__ ushort st[64][72];
    const int t = threadIdx.x;
    const int bh = blockIdx.y, l0 = blockIdx.x * 64;
    {
        const int l = t >> 2, uc = (t & 3) * 16;
        const ushort* src = &vh[((size_t)bh * 1024 + l0 + l) * 64 + uc];
        *(uint4*)&st[l][uc] = *(const uint4*)src;
        *(uint4*)&st[l][uc + 8] = *(const uint4*)(src + 8);
    }
    __syncthreads();
    {
        const int u = t >> 2, lc = (t & 3) * 16;
        ushort tmp[16];
#pragma unroll
        for (int i = 0; i < 16; ++i) tmp[i] = st[lc + i][u];
        ushort* dst = &vhT[((size_t)bh * 64 + u) * 1024 + l0 + lc];
        *(uint4*)dst = *(uint4*)&tmp[0];
        *(uint4*)(dst + 8) = *(uint4*)&tmp[8];
    }
}

// ------------------------------------------------------------- attn_fused ----
// Register-resident logits+softmax. Per block: bh, 16 q-rows.
//   logits:  wave w owns n-tiles {w, w+4, ..., w+60} -> 16x f4v in VGPRs
//   softmax: in-lane reduce over 16 tiles -> shfl_xor over 16-lane group ->
//            512B LDS cross-wave combine (rows 4g+r live in lane group g)
//   attn:    nontemporal fp32 stores straight from registers
//   P:       bf16 in 32KB LDS, XOR-swizzled; ctx reads it as MFMA A-operand
// LDS = 32KB + 512B -> 4 blocks/CU (16 waves, was 2 blocks / 8 waves).

// Swizzle: 16B-granular XOR keeps b128 reads aligned; rows 0..15 map each
// 16B column-slot to exactly 2 rows (2-way = free) for both reads and the
// scattered b16 writes (write groups land on disjoint bank octets).
__device__ __forceinline__ int pswz(int row, int b) {
    return row * 2048 + (b ^ ((row & 7) << 4) ^ ((row & 8) << 2));
}

__global__ __launch_bounds__(256, 4) void attn_fused(
    const ushort* __restrict__ qh_hi, const ushort* __restrict__ qh_lo,
    const ushort* __restrict__ kh_hi, const ushort* __restrict__ kh_lo,
    const ushort* __restrict__ vhT, float* __restrict__ attn,
    float* __restrict__ ctx) {
    __shared__ ushort Pl[16 * 1024];  // 32 KB bf16 probs
    __shared__ float redA[4][16];     // cross-wave max
    __shared__ float redB[4][16];     // cross-wave sum

    const int t = threadIdx.x, lane = t & 63, w = t >> 6;
    // XCD-bijective swizzle: 4096 blocks / 8 XCDs -> 512-block chunks; all 64
    // blocks of one bh land on the same XCD's L2.
    const int bid = blockIdx.x;
    const int sbid = (bid & 7) * 512 + (bid >> 3);
    const int bh = sbid >> 6, q0 = (sbid & 63) * 16;
    const int fr = lane & 15, g = lane >> 4, q8 = g * 8;
    const size_t hbase = (size_t)bh * 1024 * 64;

    // Q fragments (row = q0+fr), k in [0,32) and [32,64)
    const ushort* qp = &qh_hi[hbase + (size_t)(q0 + fr) * 64];
    const ushort* ql = &qh_lo[hbase + (size_t)(q0 + fr) * 64];
    const s8v qa_h0 = *(const s8v*)(qp + q8), qa_h1 = *(const s8v*)(qp + 32 + q8);
    const s8v qa_l0 = *(const s8v*)(ql + q8), qa_l1 = *(const s8v*)(ql + 32 + q8);

    // ---- logits into registers (C/D layout: col=fr, row=4g+r)
    f4v lg[16];
#pragma unroll
    for (int i = 0; i < 16; ++i) {
        const int nt = w + i * 4;
        const ushort* kp = &kh_hi[hbase + (size_t)(nt * 16 + fr) * 64];
        const ushort* kl = &kh_lo[hbase + (size_t)(nt * 16 + fr) * 64];
        const s8v kb_h0 = *(const s8v*)(kp + q8), kb_h1 = *(const s8v*)(kp + 32 + q8);
        const s8v kb_l0 = *(const s8v*)(kl + q8), kb_l1 = *(const s8v*)(kl + 32 + q8);
        f4v a0 = {}, a1 = {}, a2 = {};
        a0 = MFMA16(qa_h0, kb_h0, a0);
        a0 = MFMA16(qa_h1, kb_h1, a0);
        a1 = MFMA16(qa_h0, kb_l0, a1);
        a1 = MFMA16(qa_h1, kb_l1, a1);
        a2 = MFMA16(qa_l0, kb_h0, a2);
        a2 = MFMA16(qa_l1, kb_h1, a2);
#pragma unroll
        for (int r = 0; r < 4; ++r) lg[i][r] = (a0[r] + a1[r] + a2[r]) * 0.125f;
    }

    // ---- row max: in-lane over 16 tiles, shfl over the 16-lane group,
    //      cross-wave via redA. Row of lg[i][r] is q0 + 4g + r.
    float mx[4];
#pragma unroll
    for (int r = 0; r < 4; ++r) {
        float m = lg[0][r];
#pragma unroll
        for (int i = 1; i < 16; ++i) m = fmaxf(m, lg[i][r]);
        m = fmaxf(m, __shfl_xor(m, 1));
        m = fmaxf(m, __shfl_xor(m, 2));
        m = fmaxf(m, __shfl_xor(m, 4));
        m = fmaxf(m, __shfl_xor(m, 8));
        mx[r] = m;
    }
    if (fr == 0) {
#pragma unroll
        for (int r = 0; r < 4; ++r) redA[w][4 * g + r] = mx[r];
    }
    __syncthreads();
    float m4[4];
#pragma unroll
    for (int r = 0; r < 4; ++r)
        m4[r] = fmaxf(fmaxf(redA[0][4 * g + r], redA[1][4 * g + r]),
                      fmaxf(redA[2][4 * g + r], redA[3][4 * g + r]));

    // ---- exp + row sum (fp32 exact)
    float sm[4] = {0.f, 0.f, 0.f, 0.f};
#pragma unroll
    for (int i = 0; i < 16; ++i)
#pragma unroll
        for (int r = 0; r < 4; ++r) {
            const float e = __expf(lg[i][r] - m4[r]);
            lg[i][r] = e;
            sm[r] += e;
        }
#pragma unroll
    for (int r = 0; r < 4; ++r) {
        sm[r] += __shfl_xor(sm[r], 1);
        sm[r] += __shfl_xor(sm[r], 2);
        sm[r] += __shfl_xor(sm[r], 4);
        sm[r] += __shfl_xor(sm[r], 8);
    }
    if (fr == 0) {
#pragma unroll
        for (int r = 0; r < 4; ++r) redB[w][4 * g + r] = sm[r];
    }
    __syncthreads();
    float inv[4];
#pragma unroll
    for (int r = 0; r < 4; ++r)
        inv[r] = 1.0f / (redB[0][4 * g + r] + redB[1][4 * g + r] +
                         redB[2][4 * g + r] + redB[3][4 * g + r]);

    // ---- normalize: nontemporal attn write (fp32, never re-read) + bf16 P->LDS
    char* Pb = (char*)Pl;
    float* abase = attn + ((size_t)bh << 20) + (size_t)(q0 + 4 * g) * 1024 + fr;
#pragma unroll
    for (int i = 0; i < 16; ++i) {
        const int nt = w + i * 4;
#pragma unroll
        for (int r = 0; r < 4; ++r) {
            const float p = lg[i][r] * inv[r];
            __builtin_nontemporal_store(p, abase + (size_t)r * 1024 + nt * 16);
            *(ushort*)(Pb + pswz(4 * g + r, (nt * 16 + fr) * 2)) = f2bf(p);
        }
    }
    __syncthreads();

    // ---- ctx: wave w -> u-tile w (cols 16w..16w+15), A = P bf16 from LDS
    f4v cacc = {};
    const ushort* vp = &vhT[hbase + (size_t)(w * 16 + fr) * 1024];
#pragma unroll 4
    for (int ks = 0; ks < 32; ++ks) {
        const s8v a = *(const s8v*)(Pb + pswz(fr, ks * 64 + q8 * 2));
        const s8v b = *(const s8v*)(vp + ks * 32 + q8);
        cacc = MFMA16(a, b, cacc);
    }
#pragma unroll
    for (int r = 0; r < 4; ++r)
        ctx[((size_t)bh * 1024 + q0 + 4 * g + r) * 64 + w * 16 + fr] = cacc[r];
}

// --------------------------------------------------------------- gemm_out ----
#define LDS_PAD 68
__global__ __launch_bounds__(256) void gemm_out(const float* __restrict__ ctx,
                                                const float* __restrict__ wo,
                                                const float* __restrict__ bo,
                                                float* __restrict__ out) {
    __shared__ float As[16][LDS_PAD];
    __shared__ float Bs[16][LDS_PAD];
    const int t = threadIdx.x;
    const int tx = t & 15, ty = t >> 4;
    const int row0 = blockIdx.y * 64;

    const int am = t >> 2, ak4 = t & 3;
    const int bk = t >> 4, bn4 = t & 15;

    float acc[4][4] = {};
    for (int k0 = 0; k0 < 1024; k0 += 16) {
        const int r = row0 + am;
        const int b = r >> 10, l = r & 1023;
        const int c = k0 + ak4 * 4;
        const int h = c >> 6, d = c & 63;
        float4 a = *(const float4*)&ctx[(size_t)((b * 16 + h) * 1024 + l) * 64 + d];
        float4 bvv = *(const float4*)&wo[(size_t)(k0 + bk) * 64 + bn4 * 4];
        As[ak4 * 4 + 0][am] = a.x; As[ak4 * 4 + 1][am] = a.y;
        As[ak4 * 4 + 2][am] = a.z; As[ak4 * 4 + 3][am] = a.w;
        Bs[bk][bn4 * 4 + 0] = bvv.x; Bs[bk][bn4 * 4 + 1] = bvv.y;
        Bs[bk][bn4 * 4 + 2] = bvv.z; Bs[bk][bn4 * 4 + 3] = bvv.w;
        __syncthreads();
#pragma unroll
        for (int kk = 0; kk < 16; ++kk) {
            float av[4], bv[4];
#pragma unroll
            for (int i = 0; i < 4; ++i) av[i] = As[kk][ty * 4 + i];
#pragma unroll
            for (int j = 0; j < 4; ++j) bv[j] = Bs[kk][tx * 4 + j];
#pragma unroll
            for (int i = 0; i < 4; ++i)
#pragma unroll
                for (int j = 0; j < 4; ++j) acc[i][j] += av[i] * bv[j];
        }
        __syncthreads();
    }
#pragma unroll
    for (int i = 0; i < 4; ++i) {
        const int r = row0 + ty * 4 + i;
#pragma unroll
        for (int j = 0; j < 4; ++j) {
            const int u = tx * 4 + j;
            out[(size_t)r * 64 + u] = acc[i][j] + bo[u];
        }
    }
}

extern "C" void kernel_launch(void* const* d_in, const int* in_sizes, int n_in,
                              void* d_out, int out_size, void* d_ws, size_t ws_size,
                              hipStream_t stream) {
    const float* v_in = (const float*)d_in[0];
    const float* k_in = (const float*)d_in[1];
    const float* q_in = (const float*)d_in[2];
    const float* wq = (const float*)d_in[3];
    const float* bq = (const float*)d_in[4];
    const float* wk = (const float*)d_in[5];
    const float* bk = (const float*)d_in[6];
    const float* wv = (const float*)d_in[7];
    const float* bv = (const float*)d_in[8];
    const float* wo = (const float*)d_in[9];
    const float* bo = (const float*)d_in[10];

    float* out = (float*)d_out;
    float* attn = out + 262144;

    char* w8 = (char*)d_ws;
    const size_t MB = 1u << 20;
    ushort* wtq_hi = (ushort*)(w8 + 0 * MB);
    ushort* wtq_lo = (ushort*)(w8 + 2 * MB);
    ushort* wtk_hi = (ushort*)(w8 + 4 * MB);
    ushort* wtk_lo = (ushort*)(w8 + 6 * MB);
    ushort* wtv_hi = (ushort*)(w8 + 8 * MB);
    ushort* wtv_lo = (ushort*)(w8 + 10 * MB);
    ushort* qh_hi = (ushort*)(w8 + 12 * MB);
    ushort* qh_lo = (ushort*)(w8 + 20 * MB);
    ushort* kh_hi = (ushort*)(w8 + 28 * MB);
    ushort* kh_lo = (ushort*)(w8 + 36 * MB);
    ushort* vh_hi = (ushort*)(w8 + 44 * MB);
    ushort* vh_lo = (ushort*)(w8 + 52 * MB);
    ushort* vhT = (ushort*)(w8 + 60 * MB);
    float* ctx = (float*)(w8 + 68 * MB);

    dim3 blk(256);
    pack_wt<<<dim3(32, 32), blk, 0, stream>>>(wq, wtq_hi, wtq_lo);
    pack_wt<<<dim3(32, 32), blk, 0, stream>>>(wk, wtk_hi, wtk_lo);
    pack_wt<<<dim3(32, 32), blk, 0, stream>>>(wv, wtv_hi, wtv_lo);

    gemm_proj_mfma<true><<<dim3(8, 32), blk, 0, stream>>>(q_in, wtq_hi, wtq_lo, bq, qh_hi, qh_lo);
    gemm_proj_mfma<true><<<dim3(8, 32), blk, 0, stream>>>(k_in, wtk_hi, wtk_lo, bk, kh_hi, kh_lo);
    gemm_proj_mfma<false><<<dim3(8, 32), blk, 0, stream>>>(v_in, wtv_hi, wtv_lo, bv, vh_hi, vh_lo);

    trans_vh<<<dim3(16, 64), blk, 0, stream>>>(vh_hi, vhT);

    attn_fused<<<dim3(4096), blk, 0, stream>>>(qh_hi, qh_lo, kh_hi, kh_lo, vhT, attn, ctx);

    gemm_out<<<dim3(1, 64), blk, 0, stream>>>(ctx, wo, bo, out);
}